// Round 1
// baseline (4366.544 us; speedup 1.0000x reference)
//
#include <hip/hip_runtime.h>
#include <hip/hip_bf16.h>
#include <math.h>

// MiniGPT forward: V=32000 E=1024 H=16 L=8 T=1024 B=4, D=64. Rows M = B*T = 4096.
// All matmuls are x @ W^T with W row-major [N,K] -> "B^T input" m97-style MFMA GEMM.

#define EDIM 1024
#define TDIM 1024
#define MROWS 4096

typedef __attribute__((ext_vector_type(8))) short short8;
typedef __attribute__((ext_vector_type(8))) __bf16 bf16x8;
typedef __attribute__((ext_vector_type(4))) float f32x4;

__device__ __forceinline__ unsigned short f2bf(float f) {
  unsigned u = __float_as_uint(f);
  u += 0x7fffu + ((u >> 16) & 1u);          // RNE
  return (unsigned short)(u >> 16);
}
__device__ __forceinline__ float bf2f(unsigned short s) {
  return __uint_as_float(((unsigned)s) << 16);
}

__device__ __forceinline__ void async16(const void* g, void* l) {
  __builtin_amdgcn_global_load_lds(
      (__attribute__((address_space(1))) void*)(void*)g,
      (__attribute__((address_space(3))) void*)l,
      16, 0, 0);
}

// ---------------- fp32 -> bf16 weight conversion ----------------
__global__ void cvt_kernel(const float* __restrict__ src, unsigned short* __restrict__ dst, int n4) {
  const int stride = gridDim.x * blockDim.x;
  for (int i = blockIdx.x * blockDim.x + threadIdx.x; i < n4; i += stride) {
    const float4 v = ((const float4*)src)[i];
    ushort4 o;
    o.x = f2bf(v.x); o.y = f2bf(v.y); o.z = f2bf(v.z); o.w = f2bf(v.w);
    ((ushort4*)dst)[i] = o;
  }
}

// ---------------- embedding: x = tok_emb[idx] + pos_emb ----------------
__global__ void embed_kernel(const int* __restrict__ idx, const float* __restrict__ tok,
                             const float* __restrict__ pos, float* __restrict__ x) {
  const int i = blockIdx.x * 256 + threadIdx.x;   // float4 index, total 4096*256 = 1048576
  const int row = i >> 8;                          // 256 float4 per row (E=1024)
  const int c4 = i & 255;
  const int tkn = idx[row];
  const int t = row & (TDIM - 1);
  float4 a = ((const float4*)tok)[(size_t)tkn * 256 + c4];
  const float4 p = ((const float4*)pos)[(size_t)t * 256 + c4];
  a.x += p.x; a.y += p.y; a.z += p.z; a.w += p.w;
  ((float4*)x)[i] = a;
}

// ---------------- LayerNorm (fp32 in, bf16 out), one wave per row ----------------
__global__ __launch_bounds__(256) void ln_kernel(const float* __restrict__ x,
                                                 const float* __restrict__ g,
                                                 const float* __restrict__ bta,
                                                 unsigned short* __restrict__ out) {
  const int lane = threadIdx.x & 63;
  const int wv = threadIdx.x >> 6;
  const size_t row = (size_t)blockIdx.x * 4 + wv;
  const float* xr = x + row * EDIM;
  float4 v[4];
  float s = 0.f, s2 = 0.f;
#pragma unroll
  for (int gi = 0; gi < 4; ++gi) {
    v[gi] = ((const float4*)xr)[gi * 64 + lane];
    s  += v[gi].x + v[gi].y + v[gi].z + v[gi].w;
    s2 += v[gi].x * v[gi].x + v[gi].y * v[gi].y + v[gi].z * v[gi].z + v[gi].w * v[gi].w;
  }
#pragma unroll
  for (int off = 1; off < 64; off <<= 1) {
    s  += __shfl_xor(s, off);
    s2 += __shfl_xor(s2, off);
  }
  const float mu = s * (1.f / 1024.f);
  const float rstd = rsqrtf(s2 * (1.f / 1024.f) - mu * mu + 1e-5f);
  unsigned short* orow = out + row * EDIM;
#pragma unroll
  for (int gi = 0; gi < 4; ++gi) {
    const int c = gi * 256 + lane * 4;
    const float4 gg = *(const float4*)(g + c);
    const float4 bb = *(const float4*)(bta + c);
    ushort4 o;
    o.x = f2bf((v[gi].x - mu) * rstd * gg.x + bb.x);
    o.y = f2bf((v[gi].y - mu) * rstd * gg.y + bb.y);
    o.z = f2bf((v[gi].z - mu) * rstd * gg.z + bb.z);
    o.w = f2bf((v[gi].w - mu) * rstd * gg.w + bb.w);
    *(ushort4*)(orow + c) = o;
  }
}

// ---------------- MFMA GEMM: C[M,N] = A[M,K](bf16) @ W[N,K]^T(bf16) ----------------
// MODE 0: store bf16 | 1: +bias, exact GELU, store bf16 | 2: fp32 C += acc
// MODE 3: fp32 C += acc + bias | 4: store fp32
template <int MODE>
__global__ __launch_bounds__(256) void gemm_bt(const unsigned short* __restrict__ A,
                                               const unsigned short* __restrict__ Bw,
                                               void* __restrict__ Cv,
                                               const float* __restrict__ bias,
                                               int K, int N) {
  __shared__ unsigned short As[128 * 64];
  __shared__ unsigned short Bs[128 * 64];
  const int tid = threadIdx.x;
  const int lane = tid & 63;
  const int wv = tid >> 6;
  const int wm = wv & 1, wn = wv >> 1;
  const int row_l = lane & 15, quad = lane >> 4;
  const size_t mBase = (size_t)blockIdx.y * 128;
  const size_t nBase = (size_t)blockIdx.x * 128;

  f32x4 acc[4][4];
#pragma unroll
  for (int i = 0; i < 4; ++i)
#pragma unroll
    for (int j = 0; j < 4; ++j) acc[i][j] = (f32x4){0.f, 0.f, 0.f, 0.f};

  for (int k0 = 0; k0 < K; k0 += 64) {
    __syncthreads();
#pragma unroll
    for (int it = 0; it < 4; ++it) {
      const int cb = it * 256 + wv * 64;   // wave-uniform chunk base (16B chunks)
      const int c = cb + lane;
      const int r = c >> 3;
      const int kc = c & 7;
      async16(A  + (mBase + r) * K + k0 + kc * 8, &As[cb * 8]);
      async16(Bw + (nBase + r) * K + k0 + kc * 8, &Bs[cb * 8]);
    }
    __syncthreads();
#pragma unroll
    for (int kk = 0; kk < 64; kk += 32) {
      bf16x8 af[4], bfr[4];
#pragma unroll
      for (int mi = 0; mi < 4; ++mi)
        af[mi] = *(const bf16x8*)&As[(wm * 64 + mi * 16 + row_l) * 64 + kk + quad * 8];
#pragma unroll
      for (int ni = 0; ni < 4; ++ni)
        bfr[ni] = *(const bf16x8*)&Bs[(wn * 64 + ni * 16 + row_l) * 64 + kk + quad * 8];
#pragma unroll
      for (int mi = 0; mi < 4; ++mi)
#pragma unroll
        for (int ni = 0; ni < 4; ++ni)
          acc[mi][ni] = __builtin_amdgcn_mfma_f32_16x16x32_bf16(af[mi], bfr[ni], acc[mi][ni], 0, 0, 0);
    }
  }

#pragma unroll
  for (int mi = 0; mi < 4; ++mi) {
#pragma unroll
    for (int ni = 0; ni < 4; ++ni) {
      const size_t col = nBase + wn * 64 + ni * 16 + row_l;
      const size_t row0 = mBase + wm * 64 + mi * 16 + quad * 4;
      const f32x4 a = acc[mi][ni];
#pragma unroll
      for (int r2 = 0; r2 < 4; ++r2) {
        const size_t off = (row0 + r2) * (size_t)N + col;
        float v = a[r2];
        if constexpr (MODE == 0) {
          ((unsigned short*)Cv)[off] = f2bf(v);
        } else if constexpr (MODE == 1) {
          v += bias[col];
          v = 0.5f * v * (1.f + erff(v * 0.70710678118f));
          ((unsigned short*)Cv)[off] = f2bf(v);
        } else if constexpr (MODE == 2) {
          ((float*)Cv)[off] += v;
        } else if constexpr (MODE == 3) {
          ((float*)Cv)[off] += v + bias[col];
        } else {
          ((float*)Cv)[off] = v;
        }
      }
    }
  }
}

// ---------------- flash attention via MFMA, causal ----------------
// block = one (b, h, 64-row Q tile); 4 waves, each wave owns 16 Q rows.
// Per s-tile of 64: S = Q@K^T (8 mfma), online softmax in C-layout, P->LDS
// re-layout, O += P@V (8 mfma, V staged transposed).
__global__ __launch_bounds__(256) void attn_kernel(const unsigned short* __restrict__ qkv,
                                                   unsigned short* __restrict__ y) {
  __shared__ unsigned short Ks[64 * 72];     // K[s][d], stride 72 (+8 pad)
  __shared__ unsigned short Vt[64 * 72];     // V^T[d][s], stride 72
  __shared__ unsigned short Pl[4][16 * 72];  // per-wave P[m][s], stride 72
  const int tid = threadIdx.x;
  const int lane = tid & 63, w = tid >> 6;
  const int rl = lane & 15, quad = lane >> 4;
  const int bid = blockIdx.x;
  const int qt = bid & 15;
  const int h = (bid >> 4) & 15;
  const int b = bid >> 8;

  const float SCL = 0.125f * 1.44269504089f;  // 1/sqrt(64) * log2(e)

  // Q a-frags (held in registers): a[m=rl][k=d], d = kc*32 + quad*8 + j
  bf16x8 aq[2];
  {
    const int t = qt * 64 + w * 16 + rl;
    const unsigned short* qp = qkv + ((size_t)(b * TDIM + t)) * 3072 + h * 64 + quad * 8;
    aq[0] = *(const bf16x8*)qp;
    aq[1] = *(const bf16x8*)(qp + 32);
  }

  f32x4 oacc[4];  // O[m_out][d=di*16+rl], m_out = quad*4+r
#pragma unroll
  for (int di = 0; di < 4; ++di) oacc[di] = (f32x4){0.f, 0.f, 0.f, 0.f};
  float m[4], l[4];
#pragma unroll
  for (int r = 0; r < 4; ++r) { m[r] = -1e30f; l[r] = 0.f; }

  for (int s0 = 0; s0 <= qt * 64; s0 += 64) {
    const bool diag = (s0 == qt * 64);
    __syncthreads();  // prev-tile Ks/Vt reads done
    {
      const int sr = tid >> 2;            // s row 0..63
      const int c0 = (tid & 3) * 16;      // d chunk
      const unsigned short* kp = qkv + ((size_t)(b * TDIM + s0 + sr)) * 3072 + 1024 + h * 64 + c0;
      const short8 k0 = *(const short8*)kp;
      const short8 k1 = *(const short8*)(kp + 8);
      *(short8*)&Ks[sr * 72 + c0] = k0;
      *(short8*)&Ks[sr * 72 + c0 + 8] = k1;
      const short8 v0 = *(const short8*)(kp + 1024);
      const short8 v1 = *(const short8*)(kp + 1032);
#pragma unroll
      for (int e = 0; e < 8; ++e) {
        Vt[(c0 + e) * 72 + sr]     = (unsigned short)v0[e];
        Vt[(c0 + 8 + e) * 72 + sr] = (unsigned short)v1[e];
      }
    }
    __syncthreads();

    // ---- S = Q @ K^T : C[m][n=s], b[n=rl][k=d] = K[s][d]
    f32x4 sacc[4];
#pragma unroll
    for (int ni = 0; ni < 4; ++ni) sacc[ni] = (f32x4){0.f, 0.f, 0.f, 0.f};
#pragma unroll
    for (int kc = 0; kc < 2; ++kc) {
#pragma unroll
      for (int ni = 0; ni < 4; ++ni) {
        const bf16x8 kb = *(const bf16x8*)&Ks[(ni * 16 + rl) * 72 + kc * 32 + quad * 8];
        sacc[ni] = __builtin_amdgcn_mfma_f32_16x16x32_bf16(aq[kc], kb, sacc[ni], 0, 0, 0);
      }
    }

    // ---- online softmax. Lane holds S[row=quad*4+r][col=ni*16+rl].
    float sv[4][4];  // [ni][r]
#pragma unroll
    for (int ni = 0; ni < 4; ++ni)
#pragma unroll
      for (int r = 0; r < 4; ++r) {
        float x = sacc[ni][r] * SCL;
        if (diag && (ni * 16 + rl > w * 16 + quad * 4 + r)) x = -1e30f;
        sv[ni][r] = x;
      }
    float alpha[4];
#pragma unroll
    for (int r = 0; r < 4; ++r) {
      float tm = fmaxf(fmaxf(sv[0][r], sv[1][r]), fmaxf(sv[2][r], sv[3][r]));
#pragma unroll
      for (int off = 1; off < 16; off <<= 1) tm = fmaxf(tm, __shfl_xor(tm, off));
      const float mn = fmaxf(m[r], tm);
      alpha[r] = exp2f(m[r] - mn);
      m[r] = mn;
    }
#pragma unroll
    for (int r = 0; r < 4; ++r) {
      float rs = 0.f;
#pragma unroll
      for (int ni = 0; ni < 4; ++ni) {
        const float p = exp2f(sv[ni][r] - m[r]);
        sv[ni][r] = p;
        rs += p;
      }
#pragma unroll
      for (int off = 1; off < 16; off <<= 1) rs += __shfl_xor(rs, off);
      l[r] = l[r] * alpha[r] + rs;
    }
#pragma unroll
    for (int di = 0; di < 4; ++di)
#pragma unroll
      for (int r = 0; r < 4; ++r) oacc[di][r] *= alpha[r];

    // ---- P -> LDS (re-layout C-layout -> a-frag layout), bf16
#pragma unroll
    for (int ni = 0; ni < 4; ++ni)
#pragma unroll
      for (int r = 0; r < 4; ++r)
        Pl[w][(quad * 4 + r) * 72 + ni * 16 + rl] = f2bf(sv[ni][r]);
    __syncthreads();  // P visible across lanes (and keeps waves in step)

    // ---- O += P @ V : a[m=rl][k=s], b[n=d=rl][k=s] = V^T[d][s]
#pragma unroll
    for (int kc = 0; kc < 2; ++kc) {
      const bf16x8 pa = *(const bf16x8*)&Pl[w][rl * 72 + kc * 32 + quad * 8];
#pragma unroll
      for (int di = 0; di < 4; ++di) {
        const bf16x8 vb = *(const bf16x8*)&Vt[(di * 16 + rl) * 72 + kc * 32 + quad * 8];
        oacc[di] = __builtin_amdgcn_mfma_f32_16x16x32_bf16(pa, vb, oacc[di], 0, 0, 0);
      }
    }
  }

  // ---- epilogue: y[t][h*64+d] = O/l
  const int t0 = qt * 64 + w * 16 + quad * 4;
#pragma unroll
  for (int r = 0; r < 4; ++r) {
    const float inv = 1.f / l[r];
    unsigned short* yp = y + ((size_t)(b * TDIM + t0 + r)) * 1024 + h * 64 + rl;
#pragma unroll
    for (int di = 0; di < 4; ++di) yp[di * 16] = f2bf(oacc[di][r] * inv);
  }
}

// ---------------- host ----------------
extern "C" void kernel_launch(void* const* d_in, const int* in_sizes, int n_in,
                              void* d_out, int out_size, void* d_ws, size_t ws_size,
                              hipStream_t stream) {
  const int*   idx    = (const int*)  d_in[0];
  const float* tok    = (const float*)d_in[1];
  const float* pos    = (const float*)d_in[2];
  const float* qkv_w  = (const float*)d_in[3];
  const float* proj_w = (const float*)d_in[4];
  const float* ln1_g  = (const float*)d_in[5];
  const float* ln1_b  = (const float*)d_in[6];
  const float* ln2_g  = (const float*)d_in[7];
  const float* ln2_b  = (const float*)d_in[8];
  const float* fc1_w  = (const float*)d_in[9];
  const float* fc1_b  = (const float*)d_in[10];
  const float* fc2_w  = (const float*)d_in[11];
  const float* fc2_b  = (const float*)d_in[12];
  const float* lnf_g  = (const float*)d_in[13];
  const float* lnf_b  = (const float*)d_in[14];
  const float* head_w = (const float*)d_in[15];

  char* ws = (char*)d_ws;
  unsigned short* wq   = (unsigned short*)(ws + 0);           // 25165824 bf16
  unsigned short* wp   = (unsigned short*)(ws + 50331648);    //  8388608 bf16
  unsigned short* w1   = (unsigned short*)(ws + 67108864);    // 33554432 bf16
  unsigned short* w2   = (unsigned short*)(ws + 134217728);   // 33554432 bf16
  unsigned short* wh   = (unsigned short*)(ws + 201326592);   // 32768000 bf16
  float*          x    = (float*)         (ws + 266862592);   //  4194304 f32
  unsigned short* hbuf = (unsigned short*)(ws + 283639808);   //  4194304 bf16
  unsigned short* qkvb = (unsigned short*)(ws + 292028416);   // 12582912 bf16
  unsigned short* ybuf = (unsigned short*)(ws + 317194240);   //  4194304 bf16
  unsigned short* mid  = (unsigned short*)(ws + 325582848);   // 16777216 bf16

  cvt_kernel<<<4096, 256, 0, stream>>>(qkv_w,  wq, 25165824 / 4);
  cvt_kernel<<<4096, 256, 0, stream>>>(proj_w, wp,  8388608 / 4);
  cvt_kernel<<<4096, 256, 0, stream>>>(fc1_w,  w1, 33554432 / 4);
  cvt_kernel<<<4096, 256, 0, stream>>>(fc2_w,  w2, 33554432 / 4);
  cvt_kernel<<<4096, 256, 0, stream>>>(head_w, wh, 32768000 / 4);

  embed_kernel<<<4096, 256, 0, stream>>>(idx, tok, pos, x);

  for (int l = 0; l < 8; ++l) {
    ln_kernel<<<1024, 256, 0, stream>>>(x, ln1_g + l * 1024, ln1_b + l * 1024, hbuf);
    gemm_bt<0><<<dim3(24, 32), 256, 0, stream>>>(hbuf, wq + (size_t)l * 3145728, qkvb, nullptr, 1024, 3072);
    attn_kernel<<<1024, 256, 0, stream>>>(qkvb, ybuf);
    gemm_bt<2><<<dim3(8, 32), 256, 0, stream>>>(ybuf, wp + (size_t)l * 1048576, x, nullptr, 1024, 1024);
    ln_kernel<<<1024, 256, 0, stream>>>(x, ln2_g + l * 1024, ln2_b + l * 1024, hbuf);
    gemm_bt<1><<<dim3(32, 32), 256, 0, stream>>>(hbuf, w1 + (size_t)l * 4194304, mid, fc1_b + l * 4096, 1024, 4096);
    gemm_bt<3><<<dim3(8, 32), 256, 0, stream>>>(mid, w2 + (size_t)l * 4194304, x, fc2_b + l * 1024, 4096, 1024);
  }
  ln_kernel<<<1024, 256, 0, stream>>>(x, lnf_g, lnf_b, hbuf);
  gemm_bt<4><<<dim3(250, 32), 256, 0, stream>>>(hbuf, wh, d_out, nullptr, 1024, 32000);
}

// Round 2
// 4058.388 us; speedup vs baseline: 1.0759x; 1.0759x over previous
//
#include <hip/hip_runtime.h>
#include <hip/hip_bf16.h>
#include <math.h>

// MiniGPT forward: V=32000 E=1024 H=16 L=8 T=1024 B=4, D=64. Rows M = B*T = 4096.
// All matmuls are x @ W^T with W row-major [N,K] -> "B^T input" m97-style MFMA GEMM.
// Grid mapping: blockIdx.x = M-tile (fast axis shares the W panel), blockIdx.y = N-tile.

#define EDIM 1024
#define TDIM 1024
#define MROWS 4096

typedef __attribute__((ext_vector_type(8))) short short8;
typedef __attribute__((ext_vector_type(8))) __bf16 bf16x8;
typedef __attribute__((ext_vector_type(4))) float f32x4;

__device__ __forceinline__ unsigned short f2bf(float f) {
  unsigned u = __float_as_uint(f);
  u += 0x7fffu + ((u >> 16) & 1u);          // RNE
  return (unsigned short)(u >> 16);
}
__device__ __forceinline__ float bf2f(unsigned short s) {
  return __uint_as_float(((unsigned)s) << 16);
}

__device__ __forceinline__ void async16(const void* g, void* l) {
  __builtin_amdgcn_global_load_lds(
      (__attribute__((address_space(1))) void*)(void*)g,
      (__attribute__((address_space(3))) void*)l,
      16, 0, 0);
}

// ---------------- fp32 -> bf16 weight conversion ----------------
__global__ void cvt_kernel(const float* __restrict__ src, unsigned short* __restrict__ dst, int n4) {
  const int stride = gridDim.x * blockDim.x;
  for (int i = blockIdx.x * blockDim.x + threadIdx.x; i < n4; i += stride) {
    const float4 v = ((const float4*)src)[i];
    ushort4 o;
    o.x = f2bf(v.x); o.y = f2bf(v.y); o.z = f2bf(v.z); o.w = f2bf(v.w);
    ((ushort4*)dst)[i] = o;
  }
}

// ---------------- embedding: x = tok_emb[idx] + pos_emb ----------------
__global__ void embed_kernel(const int* __restrict__ idx, const float* __restrict__ tok,
                             const float* __restrict__ pos, float* __restrict__ x) {
  const int i = blockIdx.x * 256 + threadIdx.x;   // float4 index, total 4096*256 = 1048576
  const int row = i >> 8;                          // 256 float4 per row (E=1024)
  const int c4 = i & 255;
  const int tkn = idx[row];
  const int t = row & (TDIM - 1);
  float4 a = ((const float4*)tok)[(size_t)tkn * 256 + c4];
  const float4 p = ((const float4*)pos)[(size_t)t * 256 + c4];
  a.x += p.x; a.y += p.y; a.z += p.z; a.w += p.w;
  ((float4*)x)[i] = a;
}

// ---------------- LayerNorm (fp32 in, bf16 out), one wave per row ----------------
__global__ __launch_bounds__(256) void ln_kernel(const float* __restrict__ x,
                                                 const float* __restrict__ g,
                                                 const float* __restrict__ bta,
                                                 unsigned short* __restrict__ out) {
  const int lane = threadIdx.x & 63;
  const int wv = threadIdx.x >> 6;
  const size_t row = (size_t)blockIdx.x * 4 + wv;
  const float* xr = x + row * EDIM;
  float4 v[4];
  float s = 0.f, s2 = 0.f;
#pragma unroll
  for (int gi = 0; gi < 4; ++gi) {
    v[gi] = ((const float4*)xr)[gi * 64 + lane];
    s  += v[gi].x + v[gi].y + v[gi].z + v[gi].w;
    s2 += v[gi].x * v[gi].x + v[gi].y * v[gi].y + v[gi].z * v[gi].z + v[gi].w * v[gi].w;
  }
#pragma unroll
  for (int off = 1; off < 64; off <<= 1) {
    s  += __shfl_xor(s, off);
    s2 += __shfl_xor(s2, off);
  }
  const float mu = s * (1.f / 1024.f);
  const float rstd = rsqrtf(s2 * (1.f / 1024.f) - mu * mu + 1e-5f);
  unsigned short* orow = out + row * EDIM;
#pragma unroll
  for (int gi = 0; gi < 4; ++gi) {
    const int c = gi * 256 + lane * 4;
    const float4 gg = *(const float4*)(g + c);
    const float4 bb = *(const float4*)(bta + c);
    ushort4 o;
    o.x = f2bf((v[gi].x - mu) * rstd * gg.x + bb.x);
    o.y = f2bf((v[gi].y - mu) * rstd * gg.y + bb.y);
    o.z = f2bf((v[gi].z - mu) * rstd * gg.z + bb.z);
    o.w = f2bf((v[gi].w - mu) * rstd * gg.w + bb.w);
    *(ushort4*)(orow + c) = o;
  }
}

// ---------------- MFMA GEMM: C[M,N] = A[M,K](bf16) @ W[N,K]^T(bf16) ----------------
// MODE 0: store bf16 | 1: +bias, exact GELU, store bf16 | 2: fp32 C += acc
// MODE 3: fp32 C += acc + bias | 4: store fp32
// BN: N tile (128: wave-tile 64x64, 64: wave-tile 64x32 for narrow-N occupancy)
template <int MODE, int BN>
__global__ __launch_bounds__(256) void gemm_bt(const unsigned short* __restrict__ A,
                                               const unsigned short* __restrict__ Bw,
                                               void* __restrict__ Cv,
                                               const float* __restrict__ bias,
                                               int K, int N) {
  constexpr int NI = BN / 32;        // acc tiles in N per wave (4 or 2)
  constexpr int BITERS = BN / 32;    // B staging iterations (4 or 2)
  __shared__ unsigned short As[128 * 64];
  __shared__ unsigned short Bs[BN * 64];
  const int tid = threadIdx.x;
  const int lane = tid & 63;
  const int wv = tid >> 6;
  const int wm = wv & 1, wn = wv >> 1;
  const int wnOff = wn * (BN / 2);
  const int row_l = lane & 15, quad = lane >> 4;
  const size_t mBase = (size_t)blockIdx.x * 128;
  const size_t nBase = (size_t)blockIdx.y * BN;

  f32x4 acc[4][NI];
#pragma unroll
  for (int i = 0; i < 4; ++i)
#pragma unroll
    for (int j = 0; j < NI; ++j) acc[i][j] = (f32x4){0.f, 0.f, 0.f, 0.f};

  for (int k0 = 0; k0 < K; k0 += 64) {
    __syncthreads();
#pragma unroll
    for (int it = 0; it < 4; ++it) {
      const int cb = it * 256 + wv * 64;   // wave-uniform chunk base (16B chunks)
      const int c = cb + lane;
      async16(A + (mBase + (c >> 3)) * K + k0 + (c & 7) * 8, &As[cb * 8]);
    }
#pragma unroll
    for (int it = 0; it < BITERS; ++it) {
      const int cb = it * 256 + wv * 64;
      const int c = cb + lane;
      async16(Bw + (nBase + (c >> 3)) * K + k0 + (c & 7) * 8, &Bs[cb * 8]);
    }
    __syncthreads();
#pragma unroll
    for (int kk = 0; kk < 64; kk += 32) {
      bf16x8 af[4], bfr[NI];
#pragma unroll
      for (int mi = 0; mi < 4; ++mi)
        af[mi] = *(const bf16x8*)&As[(wm * 64 + mi * 16 + row_l) * 64 + kk + quad * 8];
#pragma unroll
      for (int ni = 0; ni < NI; ++ni)
        bfr[ni] = *(const bf16x8*)&Bs[(wnOff + ni * 16 + row_l) * 64 + kk + quad * 8];
#pragma unroll
      for (int mi = 0; mi < 4; ++mi)
#pragma unroll
        for (int ni = 0; ni < NI; ++ni)
          acc[mi][ni] = __builtin_amdgcn_mfma_f32_16x16x32_bf16(af[mi], bfr[ni], acc[mi][ni], 0, 0, 0);
    }
  }

#pragma unroll
  for (int mi = 0; mi < 4; ++mi) {
#pragma unroll
    for (int ni = 0; ni < NI; ++ni) {
      const size_t col = nBase + wnOff + ni * 16 + row_l;
      const size_t row0 = mBase + wm * 64 + mi * 16 + quad * 4;
      const f32x4 a = acc[mi][ni];
#pragma unroll
      for (int r2 = 0; r2 < 4; ++r2) {
        const size_t off = (row0 + r2) * (size_t)N + col;
        float v = a[r2];
        if constexpr (MODE == 0) {
          ((unsigned short*)Cv)[off] = f2bf(v);
        } else if constexpr (MODE == 1) {
          v += bias[col];
          v = 0.5f * v * (1.f + erff(v * 0.70710678118f));
          ((unsigned short*)Cv)[off] = f2bf(v);
        } else if constexpr (MODE == 2) {
          ((float*)Cv)[off] += v;
        } else if constexpr (MODE == 3) {
          ((float*)Cv)[off] += v + bias[col];
        } else {
          ((float*)Cv)[off] = v;
        }
      }
    }
  }
}

// ---------------- flash attention via MFMA, causal ----------------
// block = one (b, h, 64-row Q tile); 4 waves, each wave owns 16 Q rows.
// Per s-tile of 64: S = Q@K^T (8 mfma), online softmax in C-layout, P->LDS
// re-layout, O += P@V (8 mfma, V staged transposed).
__global__ __launch_bounds__(256) void attn_kernel(const unsigned short* __restrict__ qkv,
                                                   unsigned short* __restrict__ y) {
  __shared__ unsigned short Ks[64 * 72];     // K[s][d], stride 72 (+8 pad)
  __shared__ unsigned short Vt[64 * 72];     // V^T[d][s], stride 72
  __shared__ unsigned short Pl[4][16 * 72];  // per-wave P[m][s], stride 72
  const int tid = threadIdx.x;
  const int lane = tid & 63, w = tid >> 6;
  const int rl = lane & 15, quad = lane >> 4;
  const int bid = blockIdx.x;
  const int qt = bid & 15;
  const int h = (bid >> 4) & 15;
  const int b = bid >> 8;

  const float SCL = 0.125f * 1.44269504089f;  // 1/sqrt(64) * log2(e)

  // Q a-frags (held in registers): a[m=rl][k=d], d = kc*32 + quad*8 + j
  bf16x8 aq[2];
  {
    const int t = qt * 64 + w * 16 + rl;
    const unsigned short* qp = qkv + ((size_t)(b * TDIM + t)) * 3072 + h * 64 + quad * 8;
    aq[0] = *(const bf16x8*)qp;
    aq[1] = *(const bf16x8*)(qp + 32);
  }

  f32x4 oacc[4];  // O[m_out][d=di*16+rl], m_out = quad*4+r
#pragma unroll
  for (int di = 0; di < 4; ++di) oacc[di] = (f32x4){0.f, 0.f, 0.f, 0.f};
  float m[4], l[4];
#pragma unroll
  for (int r = 0; r < 4; ++r) { m[r] = -1e30f; l[r] = 0.f; }

  for (int s0 = 0; s0 <= qt * 64; s0 += 64) {
    const bool diag = (s0 == qt * 64);
    __syncthreads();  // prev-tile Ks/Vt reads done
    {
      const int sr = tid >> 2;            // s row 0..63
      const int c0 = (tid & 3) * 16;      // d chunk
      const unsigned short* kp = qkv + ((size_t)(b * TDIM + s0 + sr)) * 3072 + 1024 + h * 64 + c0;
      const short8 k0 = *(const short8*)kp;
      const short8 k1 = *(const short8*)(kp + 8);
      *(short8*)&Ks[sr * 72 + c0] = k0;
      *(short8*)&Ks[sr * 72 + c0 + 8] = k1;
      const short8 v0 = *(const short8*)(kp + 1024);
      const short8 v1 = *(const short8*)(kp + 1032);
#pragma unroll
      for (int e = 0; e < 8; ++e) {
        Vt[(c0 + e) * 72 + sr]     = (unsigned short)v0[e];
        Vt[(c0 + 8 + e) * 72 + sr] = (unsigned short)v1[e];
      }
    }
    __syncthreads();

    // ---- S = Q @ K^T : C[m][n=s], b[n=rl][k=d] = K[s][d]
    f32x4 sacc[4];
#pragma unroll
    for (int ni = 0; ni < 4; ++ni) sacc[ni] = (f32x4){0.f, 0.f, 0.f, 0.f};
#pragma unroll
    for (int kc = 0; kc < 2; ++kc) {
#pragma unroll
      for (int ni = 0; ni < 4; ++ni) {
        const bf16x8 kb = *(const bf16x8*)&Ks[(ni * 16 + rl) * 72 + kc * 32 + quad * 8];
        sacc[ni] = __builtin_amdgcn_mfma_f32_16x16x32_bf16(aq[kc], kb, sacc[ni], 0, 0, 0);
      }
    }

    // ---- online softmax. Lane holds S[row=quad*4+r][col=ni*16+rl].
    float sv[4][4];  // [ni][r]
#pragma unroll
    for (int ni = 0; ni < 4; ++ni)
#pragma unroll
      for (int r = 0; r < 4; ++r) {
        float x = sacc[ni][r] * SCL;
        if (diag && (ni * 16 + rl > w * 16 + quad * 4 + r)) x = -1e30f;
        sv[ni][r] = x;
      }
    float alpha[4];
#pragma unroll
    for (int r = 0; r < 4; ++r) {
      float tm = fmaxf(fmaxf(sv[0][r], sv[1][r]), fmaxf(sv[2][r], sv[3][r]));
#pragma unroll
      for (int off = 1; off < 16; off <<= 1) tm = fmaxf(tm, __shfl_xor(tm, off));
      const float mn = fmaxf(m[r], tm);
      alpha[r] = exp2f(m[r] - mn);
      m[r] = mn;
    }
#pragma unroll
    for (int r = 0; r < 4; ++r) {
      float rs = 0.f;
#pragma unroll
      for (int ni = 0; ni < 4; ++ni) {
        const float p = exp2f(sv[ni][r] - m[r]);
        sv[ni][r] = p;
        rs += p;
      }
#pragma unroll
      for (int off = 1; off < 16; off <<= 1) rs += __shfl_xor(rs, off);
      l[r] = l[r] * alpha[r] + rs;
    }
#pragma unroll
    for (int di = 0; di < 4; ++di)
#pragma unroll
      for (int r = 0; r < 4; ++r) oacc[di][r] *= alpha[r];

    // ---- P -> LDS (re-layout C-layout -> a-frag layout), bf16
#pragma unroll
    for (int ni = 0; ni < 4; ++ni)
#pragma unroll
      for (int r = 0; r < 4; ++r)
        Pl[w][(quad * 4 + r) * 72 + ni * 16 + rl] = f2bf(sv[ni][r]);
    __syncthreads();  // P visible across lanes (and keeps waves in step)

    // ---- O += P @ V : a[m=rl][k=s], b[n=d=rl][k=s] = V^T[d][s]
#pragma unroll
    for (int kc = 0; kc < 2; ++kc) {
      const bf16x8 pa = *(const bf16x8*)&Pl[w][rl * 72 + kc * 32 + quad * 8];
#pragma unroll
      for (int di = 0; di < 4; ++di) {
        const bf16x8 vb = *(const bf16x8*)&Vt[(di * 16 + rl) * 72 + kc * 32 + quad * 8];
        oacc[di] = __builtin_amdgcn_mfma_f32_16x16x32_bf16(pa, vb, oacc[di], 0, 0, 0);
      }
    }
  }

  // ---- epilogue: y[t][h*64+d] = O/l
  const int t0 = qt * 64 + w * 16 + quad * 4;
#pragma unroll
  for (int r = 0; r < 4; ++r) {
    const float inv = 1.f / l[r];
    unsigned short* yp = y + ((size_t)(b * TDIM + t0 + r)) * 1024 + h * 64 + rl;
#pragma unroll
    for (int di = 0; di < 4; ++di) yp[di * 16] = f2bf(oacc[di][r] * inv);
  }
}

// ---------------- host ----------------
extern "C" void kernel_launch(void* const* d_in, const int* in_sizes, int n_in,
                              void* d_out, int out_size, void* d_ws, size_t ws_size,
                              hipStream_t stream) {
  const int*   idx    = (const int*)  d_in[0];
  const float* tok    = (const float*)d_in[1];
  const float* pos    = (const float*)d_in[2];
  const float* qkv_w  = (const float*)d_in[3];
  const float* proj_w = (const float*)d_in[4];
  const float* ln1_g  = (const float*)d_in[5];
  const float* ln1_b  = (const float*)d_in[6];
  const float* ln2_g  = (const float*)d_in[7];
  const float* ln2_b  = (const float*)d_in[8];
  const float* fc1_w  = (const float*)d_in[9];
  const float* fc1_b  = (const float*)d_in[10];
  const float* fc2_w  = (const float*)d_in[11];
  const float* fc2_b  = (const float*)d_in[12];
  const float* lnf_g  = (const float*)d_in[13];
  const float* lnf_b  = (const float*)d_in[14];
  const float* head_w = (const float*)d_in[15];

  char* ws = (char*)d_ws;
  unsigned short* wq   = (unsigned short*)(ws + 0);           // 25165824 bf16
  unsigned short* wp   = (unsigned short*)(ws + 50331648);    //  8388608 bf16
  unsigned short* w1   = (unsigned short*)(ws + 67108864);    // 33554432 bf16
  unsigned short* w2   = (unsigned short*)(ws + 134217728);   // 33554432 bf16
  unsigned short* wh   = (unsigned short*)(ws + 201326592);   // 32768000 bf16
  float*          x    = (float*)         (ws + 266862592);   //  4194304 f32
  unsigned short* hbuf = (unsigned short*)(ws + 283639808);   //  4194304 bf16
  unsigned short* qkvb = (unsigned short*)(ws + 292028416);   // 12582912 bf16
  unsigned short* ybuf = (unsigned short*)(ws + 317194240);   //  4194304 bf16
  unsigned short* mid  = (unsigned short*)(ws + 325582848);   // 16777216 bf16

  cvt_kernel<<<4096, 256, 0, stream>>>(qkv_w,  wq, 25165824 / 4);
  cvt_kernel<<<4096, 256, 0, stream>>>(proj_w, wp,  8388608 / 4);
  cvt_kernel<<<4096, 256, 0, stream>>>(fc1_w,  w1, 33554432 / 4);
  cvt_kernel<<<4096, 256, 0, stream>>>(fc2_w,  w2, 33554432 / 4);
  cvt_kernel<<<4096, 256, 0, stream>>>(head_w, wh, 32768000 / 4);

  embed_kernel<<<4096, 256, 0, stream>>>(idx, tok, pos, x);

  for (int l = 0; l < 8; ++l) {
    ln_kernel<<<1024, 256, 0, stream>>>(x, ln1_g + l * 1024, ln1_b + l * 1024, hbuf);
    gemm_bt<0, 128><<<dim3(32, 24), 256, 0, stream>>>(hbuf, wq + (size_t)l * 3145728, qkvb, nullptr, 1024, 3072);
    attn_kernel<<<1024, 256, 0, stream>>>(qkvb, ybuf);
    gemm_bt<2, 64><<<dim3(32, 16), 256, 0, stream>>>(ybuf, wp + (size_t)l * 1048576, x, nullptr, 1024, 1024);
    ln_kernel<<<1024, 256, 0, stream>>>(x, ln2_g + l * 1024, ln2_b + l * 1024, hbuf);
    gemm_bt<1, 128><<<dim3(32, 32), 256, 0, stream>>>(hbuf, w1 + (size_t)l * 4194304, mid, fc1_b + l * 4096, 1024, 4096);
    gemm_bt<3, 64><<<dim3(32, 16), 256, 0, stream>>>(mid, w2 + (size_t)l * 4194304, x, fc2_b + l * 1024, 4096, 1024);
  }
  ln_kernel<<<1024, 256, 0, stream>>>(x, lnf_g, lnf_b, hbuf);
  gemm_bt<4, 128><<<dim3(32, 250), 256, 0, stream>>>(hbuf, wh, d_out, nullptr, 1024, 32000);
}